// Round 1
// baseline (354.968 us; speedup 1.0000x reference)
//
#include <hip/hip_runtime.h>
#include <hip/hip_bf16.h>

typedef __hip_bfloat16 bf16;
typedef __attribute__((ext_vector_type(8))) __bf16 bf16x8;
typedef __attribute__((ext_vector_type(4))) float f32x4;

#define MFMA16(a, b, c) __builtin_amdgcn_mfma_f32_16x16x32_bf16((a), (b), (c), 0, 0, 0)

static constexpr int B_ = 2, T_ = 2048, C_ = 1024, H_ = 16, D_ = 64;
static constexpr int BT = B_ * T_;   // 4096
static constexpr int N3 = 3 * C_;    // 3072

// ---------- prep kernels ----------

// src (K rows, N cols) fp32 -> dst (N rows, K cols) bf16   (i.e. dst = src^T)
__global__ void k_transpose_w(const float* __restrict__ src, bf16* __restrict__ dst,
                              int K, int N) {
    int i = blockIdx.x * 256 + threadIdx.x;
    if (i >= K * N) return;
    int n = i / K, r = i - n * K;
    dst[i] = __float2bfloat16(src[r * N + n]);
}

__global__ void k_convert_x(const float* __restrict__ src, bf16* __restrict__ dst, int n4) {
    int i = blockIdx.x * 256 + threadIdx.x;
    if (i >= n4) return;
    float4 v = reinterpret_cast<const float4*>(src)[i];
    dst[4 * i + 0] = __float2bfloat16(v.x);
    dst[4 * i + 1] = __float2bfloat16(v.y);
    dst[4 * i + 2] = __float2bfloat16(v.z);
    dst[4 * i + 3] = __float2bfloat16(v.w);
}

// cos/sin tables, (T, 32) each: ang = t * 10000^(-f/32)
__global__ void k_rope_table(float* __restrict__ ct, float* __restrict__ st) {
    int i = blockIdx.x * 256 + threadIdx.x;  // t*32 + f
    if (i >= T_ * 32) return;
    int t = i >> 5, f = i & 31;
    float invf = exp2f(-(float)f * 0.4152410118609203f);  // 10000^(-f/32)
    float ang = (float)t * invf;
    ct[i] = cosf(ang);
    st[i] = sinf(ang);
}

// ---------- QKV GEMM (bf16 MFMA) with fused bias + RoPE + scatter ----------
// A:  x bf16 (4096 x 1024) row-major
// Bt: Wqkv^T bf16 (3072 x 1024) row-major (N x K)
// outputs: q,k as (B,H,T,D) bf16 (RoPE'd); v transposed as (B,H,D,T) bf16
__global__ __launch_bounds__(256) void k_gemm_qkv(
    const bf16* __restrict__ A, const bf16* __restrict__ Bt,
    const float* __restrict__ bias,
    const float* __restrict__ ct, const float* __restrict__ st,
    bf16* __restrict__ q, bf16* __restrict__ kk, bf16* __restrict__ vt) {
    __shared__ bf16 lA[128 * 40];  // +8 pad: 2-way max bank conflict
    __shared__ bf16 lB[128 * 40];
    const int tid = threadIdx.x;
    const int wave = tid >> 6, lane = tid & 63;
    const int wm = wave >> 1, wn = wave & 1;
    const int l16 = lane & 15, lg = lane >> 4;
    const int m0 = blockIdx.y * 128, n0 = blockIdx.x * 128;
    const int srow = tid >> 2, skc = (tid & 3) << 3;

    f32x4 acc[4][4];
#pragma unroll
    for (int i = 0; i < 4; i++)
#pragma unroll
        for (int j = 0; j < 4; j++) acc[i][j] = (f32x4){0.f, 0.f, 0.f, 0.f};

    const bf16* Ap = A + (size_t)(m0 + srow) * 1024 + skc;
    const bf16* Bp = Bt + (size_t)(n0 + srow) * 1024 + skc;

    for (int k0 = 0; k0 < 1024; k0 += 32) {
        uint4 a0 = *(const uint4*)(Ap + k0);
        uint4 a1 = *(const uint4*)(Ap + 64 * 1024 + k0);
        uint4 b0 = *(const uint4*)(Bp + k0);
        uint4 b1 = *(const uint4*)(Bp + 64 * 1024 + k0);
        __syncthreads();
        *(uint4*)(lA + srow * 40 + skc) = a0;
        *(uint4*)(lA + (srow + 64) * 40 + skc) = a1;
        *(uint4*)(lB + srow * 40 + skc) = b0;
        *(uint4*)(lB + (srow + 64) * 40 + skc) = b1;
        __syncthreads();
        bf16x8 af[4], bfr[4];
#pragma unroll
        for (int mi = 0; mi < 4; mi++)
            af[mi] = *(const bf16x8*)(lA + (wm * 64 + mi * 16 + l16) * 40 + lg * 8);
#pragma unroll
        for (int nj = 0; nj < 4; nj++)
            bfr[nj] = *(const bf16x8*)(lB + (wn * 64 + nj * 16 + l16) * 40 + lg * 8);
#pragma unroll
        for (int mi = 0; mi < 4; mi++)
#pragma unroll
            for (int nj = 0; nj < 4; nj++)
                acc[mi][nj] = MFMA16(af[mi], bfr[nj], acc[mi][nj]);
    }

    // epilogue: bias + RoPE + scatter
    const int b = m0 >> 11;  // tile fully within one batch (2048 % 128 == 0)
#pragma unroll
    for (int mi = 0; mi < 4; mi++) {
        int mbase = m0 + wm * 64 + mi * 16 + lg * 4;
#pragma unroll
        for (int nj = 0; nj < 4; nj++) {
            int n = n0 + wn * 64 + nj * 16 + l16;
            int which = n >> 10;        // 0=q 1=k 2=v (uniform per block)
            int nq = n & 1023;
            int h = nq >> 6, d = nq & 63;
#pragma unroll
            for (int r = 0; r < 4; r++) {
                int m = mbase + r;
                int t = m & 2047;
                float v = acc[mi][nj][r] + bias[n];
                if (which == 2) {
                    vt[((size_t)(b * 16 + h) * 64 + d) * 2048 + t] = __float2bfloat16(v);
                } else {
                    float pv = acc[mi][nj ^ 2][r] + bias[n ^ 32];  // partner d^32, same lane
                    float c = ct[t * 32 + (d & 31)];
                    float s = st[t * 32 + (d & 31)];
                    float rh = (d < 32) ? -pv : pv;
                    float o = v * c + rh * s;
                    bf16* dst = (which == 0) ? q : kk;
                    dst[((size_t)(b * 16 + h) * 2048 + t) * 64 + d] = __float2bfloat16(o);
                }
            }
        }
    }
}

// ---------- flash attention (causal), bf16 MFMA, fp32 online softmax ----------
// q,k: (B,H,T,D) bf16 (RoPE'd); vt: (B,H,D,T) bf16; y: (B,T,C) bf16
__global__ __launch_bounds__(256) void k_attn(
    const bf16* __restrict__ q, const bf16* __restrict__ k,
    const bf16* __restrict__ vt, bf16* __restrict__ y) {
    __shared__ bf16 lp[4 * 16 * 40];  // per-wave 16x32 P strip, padded stride 40
    const int wave = threadIdx.x >> 6, lane = threadIdx.x & 63;
    const int l16 = lane & 15, lg = lane >> 4;
    const int bh = blockIdx.y;               // 0..31
    const int q0 = blockIdx.x * 64 + wave * 16;
    const bf16* qh = q + (size_t)bh * 2048 * 64;
    const bf16* kh = k + (size_t)bh * 2048 * 64;
    const bf16* vh = vt + (size_t)bh * 64 * 2048;
    bf16* lpw = lp + wave * (16 * 40);

    // Q fragments (rows q0+l16, K-dim = d)
    bf16x8 aq0 = *(const bf16x8*)(qh + (size_t)(q0 + l16) * 64 + lg * 8);
    bf16x8 aq1 = *(const bf16x8*)(qh + (size_t)(q0 + l16) * 64 + 32 + lg * 8);

    f32x4 acc_o[4];
#pragma unroll
    for (int i = 0; i < 4; i++) acc_o[i] = (f32x4){0.f, 0.f, 0.f, 0.f};
    float mrow[4] = {-1e30f, -1e30f, -1e30f, -1e30f};
    float lsum[4] = {0.f, 0.f, 0.f, 0.f};

    const int rowmax = q0 + 15;
    for (int kt = 0; kt <= rowmax; kt += 32) {
        // S = Q K^T for 32 kv cols (2 col-fragments)
        f32x4 s0 = (f32x4){0.f, 0.f, 0.f, 0.f};
        f32x4 s1 = (f32x4){0.f, 0.f, 0.f, 0.f};
        {
            bf16x8 bk0a = *(const bf16x8*)(kh + (size_t)(kt + l16) * 64 + lg * 8);
            bf16x8 bk0b = *(const bf16x8*)(kh + (size_t)(kt + l16) * 64 + 32 + lg * 8);
            s0 = MFMA16(aq0, bk0a, s0);
            s0 = MFMA16(aq1, bk0b, s0);
            bf16x8 bk1a = *(const bf16x8*)(kh + (size_t)(kt + 16 + l16) * 64 + lg * 8);
            bf16x8 bk1b = *(const bf16x8*)(kh + (size_t)(kt + 16 + l16) * 64 + 32 + lg * 8);
            s1 = MFMA16(aq0, bk1a, s1);
            s1 = MFMA16(aq1, bk1b, s1);
        }
        // online softmax (rows live in 16-lane groups; reduce over masks 1..8)
        float alpha_r[4];
#pragma unroll
        for (int r = 0; r < 4; r++) {
            int row = q0 + lg * 4 + r;
            int t0 = kt + l16, t1 = kt + 16 + l16;
            float v0 = s0[r] * 0.125f;
            float v1 = s1[r] * 0.125f;
            if (t0 > row) v0 = -1e30f;
            if (t1 > row) v1 = -1e30f;
            float tm = fmaxf(v0, v1);
#pragma unroll
            for (int msk = 1; msk < 16; msk <<= 1) tm = fmaxf(tm, __shfl_xor(tm, msk, 64));
            float mnew = fmaxf(mrow[r], tm);
            float alpha = __expf(mrow[r] - mnew);
            float p0 = __expf(v0 - mnew);
            float p1 = __expf(v1 - mnew);
            lsum[r] = lsum[r] * alpha + p0 + p1;
            mrow[r] = mnew;
            alpha_r[r] = alpha;
            // stage P (S-layout) into LDS
            lpw[(lg * 4 + r) * 40 + l16] = __float2bfloat16(p0);
            lpw[(lg * 4 + r) * 40 + 16 + l16] = __float2bfloat16(p1);
        }
#pragma unroll
        for (int nd = 0; nd < 4; nd++) {
#pragma unroll
            for (int r = 0; r < 4; r++) acc_o[nd][r] *= alpha_r[r];
        }
        // reload P in A-fragment layout (same-wave LDS dependency; compiler waits)
        bf16x8 ap = *(const bf16x8*)(lpw + l16 * 40 + lg * 8);
#pragma unroll
        for (int nd = 0; nd < 4; nd++) {
            bf16x8 bv = *(const bf16x8*)(vh + (size_t)(nd * 16 + l16) * 2048 + kt + lg * 8);
            acc_o[nd] = MFMA16(ap, bv, acc_o[nd]);
        }
    }

    const int b = bh >> 4, h = bh & 15;
#pragma unroll
    for (int r = 0; r < 4; r++) {
        float l = lsum[r];
#pragma unroll
        for (int msk = 1; msk < 16; msk <<= 1) l += __shfl_xor(l, msk, 64);
        float inv = 1.f / l;
        int t = q0 + lg * 4 + r;
#pragma unroll
        for (int nd = 0; nd < 4; nd++)
            y[((size_t)(b * 2048 + t)) * 1024 + h * 64 + nd * 16 + l16] =
                __float2bfloat16(acc_o[nd][r] * inv);
    }
}

// ---------- proj GEMM: out = y @ Wproj + bproj (fp32 out) ----------
__global__ __launch_bounds__(256) void k_gemm_proj(
    const bf16* __restrict__ A, const bf16* __restrict__ Bt,
    const float* __restrict__ bias, float* __restrict__ out) {
    __shared__ bf16 lA[128 * 40];
    __shared__ bf16 lB[128 * 40];
    const int tid = threadIdx.x;
    const int wave = tid >> 6, lane = tid & 63;
    const int wm = wave >> 1, wn = wave & 1;
    const int l16 = lane & 15, lg = lane >> 4;
    const int m0 = blockIdx.y * 128, n0 = blockIdx.x * 128;
    const int srow = tid >> 2, skc = (tid & 3) << 3;

    f32x4 acc[4][4];
#pragma unroll
    for (int i = 0; i < 4; i++)
#pragma unroll
        for (int j = 0; j < 4; j++) acc[i][j] = (f32x4){0.f, 0.f, 0.f, 0.f};

    const bf16* Ap = A + (size_t)(m0 + srow) * 1024 + skc;
    const bf16* Bp = Bt + (size_t)(n0 + srow) * 1024 + skc;

    for (int k0 = 0; k0 < 1024; k0 += 32) {
        uint4 a0 = *(const uint4*)(Ap + k0);
        uint4 a1 = *(const uint4*)(Ap + 64 * 1024 + k0);
        uint4 b0 = *(const uint4*)(Bp + k0);
        uint4 b1 = *(const uint4*)(Bp + 64 * 1024 + k0);
        __syncthreads();
        *(uint4*)(lA + srow * 40 + skc) = a0;
        *(uint4*)(lA + (srow + 64) * 40 + skc) = a1;
        *(uint4*)(lB + srow * 40 + skc) = b0;
        *(uint4*)(lB + (srow + 64) * 40 + skc) = b1;
        __syncthreads();
        bf16x8 af[4], bfr[4];
#pragma unroll
        for (int mi = 0; mi < 4; mi++)
            af[mi] = *(const bf16x8*)(lA + (wm * 64 + mi * 16 + l16) * 40 + lg * 8);
#pragma unroll
        for (int nj = 0; nj < 4; nj++)
            bfr[nj] = *(const bf16x8*)(lB + (wn * 64 + nj * 16 + l16) * 40 + lg * 8);
#pragma unroll
        for (int mi = 0; mi < 4; mi++)
#pragma unroll
            for (int nj = 0; nj < 4; nj++)
                acc[mi][nj] = MFMA16(af[mi], bfr[nj], acc[mi][nj]);
    }

#pragma unroll
    for (int mi = 0; mi < 4; mi++) {
        int mbase = m0 + wm * 64 + mi * 16 + lg * 4;
#pragma unroll
        for (int nj = 0; nj < 4; nj++) {
            int n = n0 + wn * 64 + nj * 16 + l16;
#pragma unroll
            for (int r = 0; r < 4; r++) {
                out[(size_t)(mbase + r) * 1024 + n] = acc[mi][nj][r] + bias[n];
            }
        }
    }
}

// ---------- launch ----------
extern "C" void kernel_launch(void* const* d_in, const int* in_sizes, int n_in,
                              void* d_out, int out_size, void* d_ws, size_t ws_size,
                              hipStream_t stream) {
    const float* x = (const float*)d_in[0];
    const float* Wqkv = (const float*)d_in[1];
    const float* bqkv = (const float*)d_in[2];
    const float* Wproj = (const float*)d_in[3];
    const float* bproj = (const float*)d_in[4];
    float* out = (float*)d_out;

    char* ws = (char*)d_ws;
    bf16* xb = (bf16*)ws;      ws += (size_t)BT * C_ * 2;          // 8 MB
    bf16* wqkvT = (bf16*)ws;   ws += (size_t)N3 * C_ * 2;          // 6 MB
    bf16* wprojT = (bf16*)ws;  ws += (size_t)C_ * C_ * 2;          // 2 MB
    bf16* qb = (bf16*)ws;      ws += (size_t)B_ * H_ * T_ * D_ * 2;
    bf16* kb = (bf16*)ws;      ws += (size_t)B_ * H_ * T_ * D_ * 2;
    bf16* vtb = (bf16*)ws;     ws += (size_t)B_ * H_ * T_ * D_ * 2;
    bf16* yb = (bf16*)ws;      ws += (size_t)BT * C_ * 2;
    float* ct = (float*)ws;    ws += (size_t)T_ * 32 * 4;
    float* st = (float*)ws;    ws += (size_t)T_ * 32 * 4;

    hipLaunchKernelGGL(k_transpose_w, dim3((N3 * C_) / 256), dim3(256), 0, stream,
                       Wqkv, wqkvT, C_, N3);
    hipLaunchKernelGGL(k_transpose_w, dim3((C_ * C_) / 256), dim3(256), 0, stream,
                       Wproj, wprojT, C_, C_);
    hipLaunchKernelGGL(k_convert_x, dim3((BT * C_ / 4) / 256), dim3(256), 0, stream,
                       x, xb, BT * C_ / 4);
    hipLaunchKernelGGL(k_rope_table, dim3((T_ * 32) / 256), dim3(256), 0, stream, ct, st);
    hipLaunchKernelGGL(k_gemm_qkv, dim3(N3 / 128, BT / 128), dim3(256), 0, stream,
                       xb, wqkvT, bqkv, ct, st, qb, kb, vtb);
    hipLaunchKernelGGL(k_attn, dim3(T_ / 64, B_ * H_), dim3(256), 0, stream,
                       qb, kb, vtb, yb);
    hipLaunchKernelGGL(k_gemm_proj, dim3(C_ / 128, BT / 128), dim3(256), 0, stream,
                       yb, wprojT, bproj, out);
}

// Round 2
// 243.689 us; speedup vs baseline: 1.4566x; 1.4566x over previous
//
#include <hip/hip_runtime.h>
#include <hip/hip_bf16.h>

typedef __hip_bfloat16 bf16;
typedef __attribute__((ext_vector_type(8))) __bf16 bf16x8;
typedef __attribute__((ext_vector_type(4))) float f32x4;
typedef unsigned short u16;

#define MFMA16(a, b, c) __builtin_amdgcn_mfma_f32_16x16x32_bf16((a), (b), (c), 0, 0, 0)

static constexpr int B_ = 2, T_ = 2048, C_ = 1024, H_ = 16, D_ = 64;
static constexpr int BT = B_ * T_;   // 4096
static constexpr int N3 = 3 * C_;    // 3072

// ---------- prep kernels ----------

// src (K rows, N cols) fp32 -> dst (N rows, K cols) bf16   (i.e. dst = src^T)
__global__ void k_transpose_w(const float* __restrict__ src, bf16* __restrict__ dst,
                              int K, int N) {
    int i = blockIdx.x * 256 + threadIdx.x;
    if (i >= K * N) return;
    int n = i / K, r = i - n * K;
    dst[i] = __float2bfloat16(src[r * N + n]);
}

__global__ void k_convert_x(const float* __restrict__ src, bf16* __restrict__ dst, int n4) {
    int i = blockIdx.x * 256 + threadIdx.x;
    if (i >= n4) return;
    float4 v = reinterpret_cast<const float4*>(src)[i];
    dst[4 * i + 0] = __float2bfloat16(v.x);
    dst[4 * i + 1] = __float2bfloat16(v.y);
    dst[4 * i + 2] = __float2bfloat16(v.z);
    dst[4 * i + 3] = __float2bfloat16(v.w);
}

// cos/sin tables, (T, 32) each: ang = t * 10000^(-f/32)
__global__ void k_rope_table(float* __restrict__ ct, float* __restrict__ st) {
    int i = blockIdx.x * 256 + threadIdx.x;  // t*32 + f
    if (i >= T_ * 32) return;
    int t = i >> 5, f = i & 31;
    float invf = exp2f(-(float)f * 0.4152410118609203f);  // 10000^(-f/32)
    float ang = (float)t * invf;
    ct[i] = cosf(ang);
    st[i] = sinf(ang);
}

// ---------- QKV GEMM (bf16 MFMA) with fused bias + RoPE + scatter ----------
__global__ __launch_bounds__(256) void k_gemm_qkv(
    const bf16* __restrict__ A, const bf16* __restrict__ Bt,
    const float* __restrict__ bias,
    const float* __restrict__ ct, const float* __restrict__ st,
    bf16* __restrict__ q, bf16* __restrict__ kk, bf16* __restrict__ vt) {
    __shared__ bf16 lA[128 * 40];  // +8 pad: 2-way max bank conflict
    __shared__ bf16 lB[128 * 40];
    const int tid = threadIdx.x;
    const int wave = tid >> 6, lane = tid & 63;
    const int wm = wave >> 1, wn = wave & 1;
    const int l16 = lane & 15, lg = lane >> 4;
    const int m0 = blockIdx.y * 128, n0 = blockIdx.x * 128;
    const int srow = tid >> 2, skc = (tid & 3) << 3;

    f32x4 acc[4][4];
#pragma unroll
    for (int i = 0; i < 4; i++)
#pragma unroll
        for (int j = 0; j < 4; j++) acc[i][j] = (f32x4){0.f, 0.f, 0.f, 0.f};

    const bf16* Ap = A + (size_t)(m0 + srow) * 1024 + skc;
    const bf16* Bp = Bt + (size_t)(n0 + srow) * 1024 + skc;

    for (int k0 = 0; k0 < 1024; k0 += 32) {
        uint4 a0 = *(const uint4*)(Ap + k0);
        uint4 a1 = *(const uint4*)(Ap + 64 * 1024 + k0);
        uint4 b0 = *(const uint4*)(Bp + k0);
        uint4 b1 = *(const uint4*)(Bp + 64 * 1024 + k0);
        __syncthreads();
        *(uint4*)(lA + srow * 40 + skc) = a0;
        *(uint4*)(lA + (srow + 64) * 40 + skc) = a1;
        *(uint4*)(lB + srow * 40 + skc) = b0;
        *(uint4*)(lB + (srow + 64) * 40 + skc) = b1;
        __syncthreads();
        bf16x8 af[4], bfr[4];
#pragma unroll
        for (int mi = 0; mi < 4; mi++)
            af[mi] = *(const bf16x8*)(lA + (wm * 64 + mi * 16 + l16) * 40 + lg * 8);
#pragma unroll
        for (int nj = 0; nj < 4; nj++)
            bfr[nj] = *(const bf16x8*)(lB + (wn * 64 + nj * 16 + l16) * 40 + lg * 8);
#pragma unroll
        for (int mi = 0; mi < 4; mi++)
#pragma unroll
            for (int nj = 0; nj < 4; nj++)
                acc[mi][nj] = MFMA16(af[mi], bfr[nj], acc[mi][nj]);
    }

    // epilogue: bias + RoPE + scatter
    const int b = m0 >> 11;  // tile fully within one batch (2048 % 128 == 0)
#pragma unroll
    for (int mi = 0; mi < 4; mi++) {
        int mbase = m0 + wm * 64 + mi * 16 + lg * 4;
#pragma unroll
        for (int nj = 0; nj < 4; nj++) {
            int n = n0 + wn * 64 + nj * 16 + l16;
            int which = n >> 10;        // 0=q 1=k 2=v (uniform per block)
            int nq = n & 1023;
            int h = nq >> 6, d = nq & 63;
#pragma unroll
            for (int r = 0; r < 4; r++) {
                int m = mbase + r;
                int t = m & 2047;
                float v = acc[mi][nj][r] + bias[n];
                if (which == 2) {
                    vt[((size_t)(b * 16 + h) * 64 + d) * 2048 + t] = __float2bfloat16(v);
                } else {
                    float pv = acc[mi][nj ^ 2][r] + bias[n ^ 32];  // partner d^32, same lane
                    float c = ct[t * 32 + (d & 31)];
                    float s = st[t * 32 + (d & 31)];
                    float rh = (d < 32) ? -pv : pv;
                    float o = v * c + rh * s;
                    bf16* dst = (which == 0) ? q : kk;
                    dst[((size_t)(b * 16 + h) * 2048 + t) * 64 + d] = __float2bfloat16(o);
                }
            }
        }
    }
}

// ---------- flash attention (causal), swapped-QK^T, in-register softmax ----------
// q,k: (B,H,T,D) bf16 (RoPE'd); vt: (B,H,D,T) bf16; y: (B,T,C) bf16
// Per wave: 32 q-rows (two 16-row groups), KV tile = 32.
// S^T = mfma(K_frag, Q_frag): lane holds q-col = lane&15, kv rows = (lane>>4)*4+r.
// O^T = mfma(Vt_frag, P_frag): lane holds q-col = lane&15, d rows = dt*16+(lane>>4)*4+r.
__global__ __launch_bounds__(256) void k_attn(
    const bf16* __restrict__ qg, const bf16* __restrict__ kg,
    const bf16* __restrict__ vtg, bf16* __restrict__ y) {
    __shared__ u16 lp[4 * 2 * 16 * 40];  // per-wave, per-q-group 16x40 P strip
    const int wave = threadIdx.x >> 6, lane = threadIdx.x & 63;
    const int l16 = lane & 15, lg = lane >> 4;
    const int bh = blockIdx.y;
    // reversed strip order: heaviest causal strips launch first
    const int q0 = (int)(gridDim.x - 1 - blockIdx.x) * 128 + wave * 32;
    const bf16* qh = qg + (size_t)bh * 2048 * 64;
    const bf16* kh = kg + (size_t)bh * 2048 * 64;
    const bf16* vh = vtg + (size_t)bh * 64 * 2048;
    u16* lpA = lp + (wave * 2 + 0) * 640;
    u16* lpB = lp + (wave * 2 + 1) * 640;

    // Q fragments (B-operand: col=q=l16, k-slots d=lg*8+j)
    bf16x8 qa0 = *(const bf16x8*)(qh + (size_t)(q0 + l16) * 64 + lg * 8);
    bf16x8 qa1 = *(const bf16x8*)(qh + (size_t)(q0 + l16) * 64 + 32 + lg * 8);
    bf16x8 qb0 = *(const bf16x8*)(qh + (size_t)(q0 + 16 + l16) * 64 + lg * 8);
    bf16x8 qb1 = *(const bf16x8*)(qh + (size_t)(q0 + 16 + l16) * 64 + 32 + lg * 8);

    f32x4 oA[4], oB[4];
#pragma unroll
    for (int i = 0; i < 4; i++) {
        oA[i] = (f32x4){0.f, 0.f, 0.f, 0.f};
        oB[i] = (f32x4){0.f, 0.f, 0.f, 0.f};
    }
    float mA = -1e30f, mB = -1e30f, lsA = 0.f, lsB = 0.f;
    const int qrowA = q0 + l16, qrowB = q0 + 16 + l16;

    auto sm_pv = [&](f32x4 slo, f32x4 shi, float& m, float& lsum, f32x4* o,
                     u16* lpg, int qrow, int kt,
                     bf16x8 vf0, bf16x8 vf1, bf16x8 vf2, bf16x8 vf3) {
        float vv[8];
#pragma unroll
        for (int r = 0; r < 4; r++) {
            int kvlo = kt + lg * 4 + r;
            vv[r]     = (kvlo <= qrow)      ? slo[r] * 0.125f : -1e30f;
            vv[4 + r] = (kvlo + 16 <= qrow) ? shi[r] * 0.125f : -1e30f;
        }
        float pm = vv[0];
#pragma unroll
        for (int j = 1; j < 8; j++) pm = fmaxf(pm, vv[j]);
        pm = fmaxf(pm, __shfl_xor(pm, 16, 64));
        pm = fmaxf(pm, __shfl_xor(pm, 32, 64));
        float mnew = fmaxf(m, pm);
        float alpha = __expf(m - mnew);
        m = mnew;
        float ps = 0.f;
        u16 pb[8];
#pragma unroll
        for (int j = 0; j < 8; j++) {
            float p = __expf(vv[j] - mnew);
            ps += p;
            pb[j] = __builtin_bit_cast(u16, __float2bfloat16(p));
        }
        lsum = lsum * alpha + ps;
        // stage P: [q=l16][kv] row-major, stride 40 (2-way bank alias = free)
        *(ushort4*)(lpg + l16 * 40 + lg * 4)      = make_ushort4(pb[0], pb[1], pb[2], pb[3]);
        *(ushort4*)(lpg + l16 * 40 + 16 + lg * 4) = make_ushort4(pb[4], pb[5], pb[6], pb[7]);
#pragma unroll
        for (int dt = 0; dt < 4; dt++)
#pragma unroll
            for (int r = 0; r < 4; r++) o[dt][r] *= alpha;
        // P as B-fragment: col=q=l16, k-slots kv=lg*8+j (same-wave LDS dep; compiler waits)
        bf16x8 pf = *(const bf16x8*)((const __bf16*)lpg + l16 * 40 + lg * 8);
        o[0] = MFMA16(vf0, pf, o[0]);
        o[1] = MFMA16(vf1, pf, o[1]);
        o[2] = MFMA16(vf2, pf, o[2]);
        o[3] = MFMA16(vf3, pf, o[3]);
    };

    const f32x4 z = (f32x4){0.f, 0.f, 0.f, 0.f};
    for (int kt = 0; kt <= q0 + 31; kt += 32) {
        // K fragments (A-operand: row=kv=l16(+16), k-slots d=lg*8+j)
        const bf16* kp = kh + (size_t)(kt + l16) * 64 + lg * 8;
        bf16x8 k0a = *(const bf16x8*)(kp);
        bf16x8 k0b = *(const bf16x8*)(kp + 32);
        bf16x8 k1a = *(const bf16x8*)(kp + 16 * 64);
        bf16x8 k1b = *(const bf16x8*)(kp + 16 * 64 + 32);
        // V^T fragments (A-operand: row=d=l16+dt*16, k-slots kv=lg*8+j)
        const bf16* vp = vh + (size_t)l16 * 2048 + kt + lg * 8;
        bf16x8 vf0 = *(const bf16x8*)(vp);
        bf16x8 vf1 = *(const bf16x8*)(vp + (size_t)16 * 2048);
        bf16x8 vf2 = *(const bf16x8*)(vp + (size_t)32 * 2048);
        bf16x8 vf3 = *(const bf16x8*)(vp + (size_t)48 * 2048);

        // group A
        f32x4 slo = MFMA16(k0a, qa0, z); slo = MFMA16(k0b, qa1, slo);
        f32x4 shi = MFMA16(k1a, qa0, z); shi = MFMA16(k1b, qa1, shi);
        sm_pv(slo, shi, mA, lsA, oA, lpA, qrowA, kt, vf0, vf1, vf2, vf3);
        // group B
        f32x4 tlo = MFMA16(k0a, qb0, z); tlo = MFMA16(k0b, qb1, tlo);
        f32x4 thi = MFMA16(k1a, qb0, z); thi = MFMA16(k1b, qb1, thi);
        sm_pv(tlo, thi, mB, lsB, oB, lpB, qrowB, kt, vf0, vf1, vf2, vf3);
    }

    const int b = bh >> 4, h = bh & 15;
    auto wout = [&](float lsum, const f32x4* o, int t) {
        float l = lsum;
        l += __shfl_xor(l, 16, 64);
        l += __shfl_xor(l, 32, 64);
        float inv = 1.f / l;
        bf16* yp = y + ((size_t)(b * 2048 + t)) * 1024 + h * 64 + lg * 4;
#pragma unroll
        for (int dt = 0; dt < 4; dt++) {
            *(ushort4*)(yp + dt * 16) = make_ushort4(
                __builtin_bit_cast(u16, __float2bfloat16(o[dt][0] * inv)),
                __builtin_bit_cast(u16, __float2bfloat16(o[dt][1] * inv)),
                __builtin_bit_cast(u16, __float2bfloat16(o[dt][2] * inv)),
                __builtin_bit_cast(u16, __float2bfloat16(o[dt][3] * inv)));
        }
    };
    wout(lsA, oA, q0 + l16);
    wout(lsB, oB, q0 + 16 + l16);
}

// ---------- proj GEMM: out = y @ Wproj + bproj (fp32 out) ----------
__global__ __launch_bounds__(256) void k_gemm_proj(
    const bf16* __restrict__ A, const bf16* __restrict__ Bt,
    const float* __restrict__ bias, float* __restrict__ out) {
    __shared__ bf16 lA[128 * 40];
    __shared__ bf16 lB[128 * 40];
    const int tid = threadIdx.x;
    const int wave = tid >> 6, lane = tid & 63;
    const int wm = wave >> 1, wn = wave & 1;
    const int l16 = lane & 15, lg = lane >> 4;
    const int m0 = blockIdx.y * 128, n0 = blockIdx.x * 128;
    const int srow = tid >> 2, skc = (tid & 3) << 3;

    f32x4 acc[4][4];
#pragma unroll
    for (int i = 0; i < 4; i++)
#pragma unroll
        for (int j = 0; j < 4; j++) acc[i][j] = (f32x4){0.f, 0.f, 0.f, 0.f};

    const bf16* Ap = A + (size_t)(m0 + srow) * 1024 + skc;
    const bf16* Bp = Bt + (size_t)(n0 + srow) * 1024 + skc;

    for (int k0 = 0; k0 < 1024; k0 += 32) {
        uint4 a0 = *(const uint4*)(Ap + k0);
        uint4 a1 = *(const uint4*)(Ap + 64 * 1024 + k0);
        uint4 b0 = *(const uint4*)(Bp + k0);
        uint4 b1 = *(const uint4*)(Bp + 64 * 1024 + k0);
        __syncthreads();
        *(uint4*)(lA + srow * 40 + skc) = a0;
        *(uint4*)(lA + (srow + 64) * 40 + skc) = a1;
        *(uint4*)(lB + srow * 40 + skc) = b0;
        *(uint4*)(lB + (srow + 64) * 40 + skc) = b1;
        __syncthreads();
        bf16x8 af[4], bfr[4];
#pragma unroll
        for (int mi = 0; mi < 4; mi++)
            af[mi] = *(const bf16x8*)(lA + (wm * 64 + mi * 16 + l16) * 40 + lg * 8);
#pragma unroll
        for (int nj = 0; nj < 4; nj++)
            bfr[nj] = *(const bf16x8*)(lB + (wn * 64 + nj * 16 + l16) * 40 + lg * 8);
#pragma unroll
        for (int mi = 0; mi < 4; mi++)
#pragma unroll
            for (int nj = 0; nj < 4; nj++)
                acc[mi][nj] = MFMA16(af[mi], bfr[nj], acc[mi][nj]);
    }

#pragma unroll
    for (int mi = 0; mi < 4; mi++) {
        int mbase = m0 + wm * 64 + mi * 16 + lg * 4;
#pragma unroll
        for (int nj = 0; nj < 4; nj++) {
            int n = n0 + wn * 64 + nj * 16 + l16;
#pragma unroll
            for (int r = 0; r < 4; r++) {
                out[(size_t)(mbase + r) * 1024 + n] = acc[mi][nj][r] + bias[n];
            }
        }
    }
}

// ---------- launch ----------
extern "C" void kernel_launch(void* const* d_in, const int* in_sizes, int n_in,
                              void* d_out, int out_size, void* d_ws, size_t ws_size,
                              hipStream_t stream) {
    const float* x = (const float*)d_in[0];
    const float* Wqkv = (const float*)d_in[1];
    const float* bqkv = (const float*)d_in[2];
    const float* Wproj = (const float*)d_in[3];
    const float* bproj = (const float*)d_in[4];
    float* out = (float*)d_out;

    char* ws = (char*)d_ws;
    bf16* xb = (bf16*)ws;      ws += (size_t)BT * C_ * 2;          // 8 MB
    bf16* wqkvT = (bf16*)ws;   ws += (size_t)N3 * C_ * 2;          // 6 MB
    bf16* wprojT = (bf16*)ws;  ws += (size_t)C_ * C_ * 2;          // 2 MB
    bf16* qb = (bf16*)ws;      ws += (size_t)B_ * H_ * T_ * D_ * 2;
    bf16* kb = (bf16*)ws;      ws += (size_t)B_ * H_ * T_ * D_ * 2;
    bf16* vtb = (bf16*)ws;     ws += (size_t)B_ * H_ * T_ * D_ * 2;
    bf16* yb = (bf16*)ws;      ws += (size_t)BT * C_ * 2;
    float* ct = (float*)ws;    ws += (size_t)T_ * 32 * 4;
    float* st = (float*)ws;    ws += (size_t)T_ * 32 * 4;

    hipLaunchKernelGGL(k_transpose_w, dim3((N3 * C_) / 256), dim3(256), 0, stream,
                       Wqkv, wqkvT, C_, N3);
    hipLaunchKernelGGL(k_transpose_w, dim3((C_ * C_) / 256), dim3(256), 0, stream,
                       Wproj, wprojT, C_, C_);
    hipLaunchKernelGGL(k_convert_x, dim3((BT * C_ / 4) / 256), dim3(256), 0, stream,
                       x, xb, BT * C_ / 4);
    hipLaunchKernelGGL(k_rope_table, dim3((T_ * 32) / 256), dim3(256), 0, stream, ct, st);
    hipLaunchKernelGGL(k_gemm_qkv, dim3(N3 / 128, BT / 128), dim3(256), 0, stream,
                       xb, wqkvT, bqkv, ct, st, qb, kb, vtb);
    hipLaunchKernelGGL(k_attn, dim3(T_ / 128, B_ * H_), dim3(256), 0, stream,
                       qb, kb, vtb, yb);
    hipLaunchKernelGGL(k_gemm_proj, dim3(C_ / 128, BT / 128), dim3(256), 0, stream,
                       yb, wprojT, bproj, out);
}

// Round 8
// 203.302 us; speedup vs baseline: 1.7460x; 1.1987x over previous
//
#include <hip/hip_runtime.h>
#include <hip/hip_bf16.h>

typedef __hip_bfloat16 bf16;
typedef __attribute__((ext_vector_type(8))) __bf16 bf16x8;
typedef __attribute__((ext_vector_type(4))) __bf16 bf16x4;
typedef __attribute__((ext_vector_type(4))) float f32x4;
typedef unsigned short u16;

#define MFMA16(a, b, c) __builtin_amdgcn_mfma_f32_16x16x32_bf16((a), (b), (c), 0, 0, 0)

static constexpr int B_ = 2, T_ = 2048, C_ = 1024, H_ = 16, D_ = 64;
static constexpr int BT = B_ * T_;   // 4096
static constexpr int N3 = 3 * C_;    // 3072

__device__ __forceinline__ void gload16(void* lds, const void* g) {
    __builtin_amdgcn_global_load_lds(
        (const __attribute__((address_space(1))) unsigned int*)g,
        (__attribute__((address_space(3))) unsigned int*)lds, 16, 0, 0);
}

__device__ __forceinline__ u16 bb(float x) {
    return __builtin_bit_cast(u16, __float2bfloat16(x));
}

// ---------- prep kernels ----------

// src (K rows, N cols) fp32 -> dst (N rows, K cols) bf16, tiled via LDS
__global__ void k_transpose_w(const float* __restrict__ src, bf16* __restrict__ dst,
                              int K, int N) {
    __shared__ float t[32][33];
    int bx = blockIdx.x * 32;  // n offset
    int by = blockIdx.y * 32;  // k offset
    int tx = threadIdx.x & 31, ty = threadIdx.x >> 5;  // 256 thr: ty 0..7
#pragma unroll
    for (int i = 0; i < 32; i += 8)
        t[ty + i][tx] = src[(size_t)(by + ty + i) * N + bx + tx];
    __syncthreads();
#pragma unroll
    for (int i = 0; i < 32; i += 8)
        dst[(size_t)(bx + ty + i) * K + by + tx] = __float2bfloat16(t[tx][ty + i]);
}

__global__ void k_convert_x(const float* __restrict__ src, bf16* __restrict__ dst, int n4) {
    int i = blockIdx.x * 256 + threadIdx.x;
    if (i >= n4) return;
    float4 v = reinterpret_cast<const float4*>(src)[i];
    dst[4 * i + 0] = __float2bfloat16(v.x);
    dst[4 * i + 1] = __float2bfloat16(v.y);
    dst[4 * i + 2] = __float2bfloat16(v.z);
    dst[4 * i + 3] = __float2bfloat16(v.w);
}

// cos/sin tables, (T, 32) each: ang = t * 10000^(-f/32)
__global__ void k_rope_table(float* __restrict__ ct, float* __restrict__ st) {
    int i = blockIdx.x * 256 + threadIdx.x;  // t*32 + f
    if (i >= T_ * 32) return;
    int t = i >> 5, f = i & 31;
    float invf = exp2f(-(float)f * 0.4152410118609203f);  // 10000^(-f/32)
    float ang = (float)t * invf;
    ct[i] = cosf(ang);
    st[i] = sinf(ang);
}

// ---------- QKV GEMM (m97 structure: global_load_lds w=16, linear LDS) ----------
__global__ __launch_bounds__(256) void k_gemm_qkv(
    const bf16* __restrict__ A, const bf16* __restrict__ Bt,
    const float* __restrict__ bias,
    const float* __restrict__ ct, const float* __restrict__ st,
    bf16* __restrict__ q, bf16* __restrict__ kk, bf16* __restrict__ vt) {
    __shared__ bf16 lA[128 * 32];
    __shared__ bf16 lB[128 * 32];
    const int tid = threadIdx.x;
    const int wave = tid >> 6, lane = tid & 63;
    const int wm = wave >> 1, wn = wave & 1;
    const int l16 = lane & 15, lg = lane >> 4;
    const int m0 = blockIdx.y * 128, n0 = blockIdx.x * 128;

    f32x4 acc[4][4];
#pragma unroll
    for (int i = 0; i < 4; i++)
#pragma unroll
        for (int j = 0; j < 4; j++) acc[i][j] = (f32x4){0.f, 0.f, 0.f, 0.f};

    const bf16* gA = A + (size_t)(m0 + wave * 32 + (lane >> 2)) * 1024 + (lane & 3) * 8;
    const bf16* gB = Bt + (size_t)(n0 + wave * 32 + (lane >> 2)) * 1024 + (lane & 3) * 8;
    bf16* sA = lA + wave * 1024;
    bf16* sB = lB + wave * 1024;

    for (int k0 = 0; k0 < 1024; k0 += 32) {
        __syncthreads();
        gload16(sA, gA + k0);
        gload16(sA + 512, gA + (size_t)16 * 1024 + k0);
        gload16(sB, gB + k0);
        gload16(sB + 512, gB + (size_t)16 * 1024 + k0);
        __syncthreads();
        bf16x8 af[4], bfr[4];
#pragma unroll
        for (int mi = 0; mi < 4; mi++)
            af[mi] = *(const bf16x8*)(lA + (wm * 64 + mi * 16 + l16) * 32 + lg * 8);
#pragma unroll
        for (int nj = 0; nj < 4; nj++)
            bfr[nj] = *(const bf16x8*)(lB + (wn * 64 + nj * 16 + l16) * 32 + lg * 8);
#pragma unroll
        for (int mi = 0; mi < 4; mi++)
#pragma unroll
            for (int nj = 0; nj < 4; nj++)
                acc[mi][nj] = MFMA16(af[mi], bfr[nj], acc[mi][nj]);
    }

    // epilogue: bias + RoPE + scatter
    const int b = m0 >> 11;
#pragma unroll
    for (int mi = 0; mi < 4; mi++) {
        int mbase = m0 + wm * 64 + mi * 16 + lg * 4;
#pragma unroll
        for (int nj = 0; nj < 4; nj++) {
            int n = n0 + wn * 64 + nj * 16 + l16;
            int which = n >> 10;        // 0=q 1=k 2=v (uniform per block)
            int nq = n & 1023;
            int h = nq >> 6, d = nq & 63;
#pragma unroll
            for (int r = 0; r < 4; r++) {
                int m = mbase + r;
                int t = m & 2047;
                float v = acc[mi][nj][r] + bias[n];
                if (which == 2) {
                    vt[((size_t)(b * 16 + h) * 64 + d) * 2048 + t] = __float2bfloat16(v);
                } else {
                    float pv = acc[mi][nj ^ 2][r] + bias[n ^ 32];  // partner d^32, same lane
                    float c = ct[t * 32 + (d & 31)];
                    float s = st[t * 32 + (d & 31)];
                    float rh = (d < 32) ? -pv : pv;
                    float o = v * c + rh * s;
                    bf16* dst = (which == 0) ? q : kk;
                    dst[((size_t)(b * 16 + h) * 2048 + t) * 64 + d] = __float2bfloat16(o);
                }
            }
        }
    }
}

// ---------- flash attention: R6 structure + R1-exact softmax numerics ----------
// (ablation: no defer-max, no log2 domain, no Q prescale — isolate the numeric block)
// Swapped QK^T: S^T[kv][q] = mfma16(K_frag, Q_frag); C/D col=l16(q), row=4lg+r(kv).
// PV: O[d][q] = mfma16(V_perm, P_as_owned); V slot (lg,j) reads kv c(lg,j) =
//   {j<4: 4lg+j; j>=4: 16+4lg+(j&3)} matching P ownership. Zero LDS/barriers.
__global__ __launch_bounds__(256, 2) void k_attn(
    const bf16* __restrict__ qg, const bf16* __restrict__ kg,
    const bf16* __restrict__ vtg, bf16* __restrict__ y) {
    const int wave = threadIdx.x >> 6, lane = threadIdx.x & 63;
    const int l16 = lane & 15, lg = lane >> 4;
    const int bh = blockIdx.y;
    const int strip = (blockIdx.y < 16) ? (int)blockIdx.x : 15 - (int)blockIdx.x;
    const int q0 = strip * 128 + wave * 32;
    const bf16* qh = qg + (size_t)bh * (2048 * 64);
    const bf16* kh = kg + (size_t)bh * (2048 * 64);
    const bf16* vh = vtg + (size_t)bh * (64 * 2048);

    // Q B-frags (2 q-groups x 2 d-halves), RAW bf16 (no prescale)
    bf16x8 qf[2][2];
#pragma unroll
    for (int g = 0; g < 2; g++)
#pragma unroll
        for (int h = 0; h < 2; h++)
            qf[g][h] = *(const bf16x8*)(qh + (size_t)(q0 + 16 * g + l16) * 64 + 32 * h + 8 * lg);

    f32x4 o[2][4];
#pragma unroll
    for (int g = 0; g < 2; g++)
#pragma unroll
        for (int dt = 0; dt < 4; dt++) o[g][dt] = (f32x4){0.f, 0.f, 0.f, 0.f};
    float mm[2] = {-1e30f, -1e30f}, ls[2] = {0.f, 0.f};

    bf16x8 kf[2][2], vf[4];
    auto loadK = [&](int kt, bf16x8 kfo[2][2]) {
#pragma unroll
        for (int t = 0; t < 2; t++) {
            const bf16* kp = kh + (size_t)(kt + 16 * t + l16) * 64 + 8 * lg;
            kfo[t][0] = *(const bf16x8*)(kp);
            kfo[t][1] = *(const bf16x8*)(kp + 32);
        }
    };
    auto loadV = [&](int kt, bf16x8 vfo[4]) {
#pragma unroll
        for (int dt = 0; dt < 4; dt++) {
            const bf16* vp = vh + (size_t)(16 * dt + l16) * 2048 + kt;
            bf16x4 lo = *(const bf16x4*)(vp + 4 * lg);
            bf16x4 hi = *(const bf16x4*)(vp + 16 + 4 * lg);
            vfo[dt] = __builtin_shufflevector(lo, hi, 0, 1, 2, 3, 4, 5, 6, 7);
        }
    };

    const f32x4 z = (f32x4){0.f, 0.f, 0.f, 0.f};
    auto tile = [&](bf16x8 kfi[2][2], bf16x8 vfi[4], bool diag) {
        f32x4 s[2][2];
#pragma unroll
        for (int g = 0; g < 2; g++)
#pragma unroll
            for (int t = 0; t < 2; t++) {
                f32x4 acc = MFMA16(kfi[t][0], qf[g][0], z);
                s[g][t] = MFMA16(kfi[t][1], qf[g][1], acc);
            }
#pragma unroll
        for (int g = 0; g < 2; g++) {
            float p[8];
#pragma unroll
            for (int t = 0; t < 2; t++)
#pragma unroll
                for (int r = 0; r < 4; r++) {
                    float v = s[g][t][r] * 0.125f;
                    if (diag && (16 * t + 4 * lg + r > 16 * g + l16)) v = -1e30f;
                    p[4 * t + r] = v;
                }
            float pm = p[0];
#pragma unroll
            for (int i = 1; i < 8; i++) pm = fmaxf(pm, p[i]);
            pm = fmaxf(pm, __shfl_xor(pm, 16, 64));
            pm = fmaxf(pm, __shfl_xor(pm, 32, 64));
            // R1-exact: always rescale (no defer gate), e-domain
            float mn = fmaxf(mm[g], pm);
            float al = __expf(mm[g] - mn);
#pragma unroll
            for (int dt = 0; dt < 4; dt++) o[g][dt] *= al;
            ls[g] *= al;
            mm[g] = mn;
            float ps = 0.f;
#pragma unroll
            for (int i = 0; i < 8; i++) {
                p[i] = __expf(p[i] - mn);
                ps += p[i];
            }
            ls[g] += ps;
            bf16x8 pf;
#pragma unroll
            for (int j = 0; j < 8; j++)
                pf[j] = __builtin_bit_cast(__bf16, __float2bfloat16(p[j]));
#pragma unroll
            for (int dt = 0; dt < 4; dt++) o[g][dt] = MFMA16(vfi[dt], pf, o[g][dt]);
        }
    };

    loadK(0, kf);
    loadV(0, vf);
    for (int kt = 32; kt <= q0; kt += 32) {
        bf16x8 nkf[2][2], nvf[4];
        loadK(kt, nkf);          // prefetch next tile
        loadV(kt, nvf);
        tile(kf, vf, false);
#pragma unroll
        for (int t = 0; t < 2; t++) { kf[t][0] = nkf[t][0]; kf[t][1] = nkf[t][1]; }
#pragma unroll
        for (int dt = 0; dt < 4; dt++) vf[dt] = nvf[dt];
    }
    tile(kf, vf, true);          // diagonal tile

    const int b = bh >> 4, h = bh & 15;
#pragma unroll
    for (int g = 0; g < 2; g++) {
        float lt = ls[g];
        lt += __shfl_xor(lt, 16, 64);
        lt += __shfl_xor(lt, 32, 64);
        float inv = 1.f / lt;
        bf16* yp = y + ((size_t)(b * 2048 + q0 + 16 * g + l16)) * 1024 + h * 64 + 4 * lg;
#pragma unroll
        for (int dt = 0; dt < 4; dt++) {
            *(ushort4*)(yp + 16 * dt) = make_ushort4(
                bb(o[g][dt][0] * inv), bb(o[g][dt][1] * inv),
                bb(o[g][dt][2] * inv), bb(o[g][dt][3] * inv));
        }
    }
}

// ---------- proj GEMM (m97 structure): out = y @ Wproj + bproj (fp32 out) ----------
__global__ __launch_bounds__(256) void k_gemm_proj(
    const bf16* __restrict__ A, const bf16* __restrict__ Bt,
    const float* __restrict__ bias, float* __restrict__ out) {
    __shared__ bf16 lA[128 * 32];
    __shared__ bf16 lB[128 * 32];
    const int tid = threadIdx.x;
    const int wave = tid >> 6, lane = tid & 63;
    const int wm = wave >> 1, wn = wave & 1;
    const int l16 = lane & 15, lg = lane >> 4;
    const int m0 = blockIdx.y * 128, n0 = blockIdx.x * 128;

    f32x4 acc[4][4];
#pragma unroll
    for (int i = 0; i < 4; i++)
#pragma unroll
        for (int j = 0; j < 4; j++) acc[i][j] = (f32x4){0.f, 0.f, 0.f, 0.f};

    const bf16* gA = A + (size_t)(m0 + wave * 32 + (lane >> 2)) * 1024 + (lane & 3) * 8;
    const bf16* gB = Bt + (size_t)(n0 + wave * 32 + (lane >> 2)) * 1024 + (lane & 3) * 8;
    bf16* sA = lA + wave * 1024;
    bf16* sB = lB + wave * 1024;

    for (int k0 = 0; k0 < 1024; k0 += 32) {
        __syncthreads();
        gload16(sA, gA + k0);
        gload16(sA + 512, gA + (size_t)16 * 1024 + k0);
        gload16(sB, gB + k0);
        gload16(sB + 512, gB + (size_t)16 * 1024 + k0);
        __syncthreads();
        bf16x8 af[4], bfr[4];
#pragma unroll
        for (int mi = 0; mi < 4; mi++)
            af[mi] = *(const bf16x8*)(lA + (wm * 64 + mi * 16 + l16) * 32 + lg * 8);
#pragma unroll
        for (int nj = 0; nj < 4; nj++)
            bfr[nj] = *(const bf16x8*)(lB + (wn * 64 + nj * 16 + l16) * 32 + lg * 8);
#pragma unroll
        for (int mi = 0; mi < 4; mi++)
#pragma unroll
            for (int nj = 0; nj < 4; nj++)
                acc[mi][nj] = MFMA16(af[mi], bfr[nj], acc[mi][nj]);
    }

#pragma unroll
    for (int mi = 0; mi < 4; mi++) {
        int mbase = m0 + wm * 64 + mi * 16 + lg * 4;
#pragma unroll
        for (int nj = 0; nj < 4; nj++) {
            int n = n0 + wn * 64 + nj * 16 + l16;
#pragma unroll
            for (int r = 0; r < 4; r++) {
                out[(size_t)(mbase + r) * 1024 + n] = acc[mi][nj][r] + bias[n];
            }
        }
    }
}

// ---------- launch ----------
extern "C" void kernel_launch(void* const* d_in, const int* in_sizes, int n_in,
                              void* d_out, int out_size, void* d_ws, size_t ws_size,
                              hipStream_t stream) {
    const float* x = (const float*)d_in[0];
    const float* Wqkv = (const float*)d_in[1];
    const float* bqkv = (const float*)d_in[2];
    const float* Wproj = (const float*)d_in[3];
    const float* bproj = (const float*)d_in[4];
    float* out = (float*)d_out;

    char* ws = (char*)d_ws;
    bf16* xb = (bf16*)ws;      ws += (size_t)BT * C_ * 2;
    bf16* wqkvT = (bf16*)ws;   ws += (size_t)N3 * C_ * 2;
    bf16* wprojT = (bf16*)ws;  ws += (size_t)C_ * C_ * 2;
    bf16* qb = (bf16*)ws;      ws += (size_t)B_ * H_ * T_ * D_ * 2;
    bf16* kb = (bf16*)ws;      ws += (size_t)B_ * H_ * T_ * D_ * 2;
    bf16* vtb = (bf16*)ws;     ws += (size_t)B_ * H_ * T_ * D_ * 2;
    bf16* yb = (bf16*)ws;      ws += (size_t)BT * C_ * 2;
    float* ct = (float*)ws;    ws += (size_t)T_ * 32 * 4;
    float* st = (float*)ws;    ws += (size_t)T_ * 32 * 4;

    hipLaunchKernelGGL(k_transpose_w, dim3(N3 / 32, C_ / 32), dim3(256), 0, stream,
                       Wqkv, wqkvT, C_, N3);
    hipLaunchKernelGGL(k_transpose_w, dim3(C_ / 32, C_ / 32), dim3(256), 0, stream,
                       Wproj, wprojT, C_, C_);
    hipLaunchKernelGGL(k_convert_x, dim3((BT * C_ / 4) / 256), dim3(256), 0, stream,
                       x, xb, BT * C_ / 4);
    hipLaunchKernelGGL(k_rope_table, dim3((T_ * 32) / 256), dim3(256), 0, stream, ct, st);
    hipLaunchKernelGGL(k_gemm_qkv, dim3(N3 / 128, BT / 128), dim3(256), 0, stream,
                       xb, wqkvT, bqkv, ct, st, qb, kb, vtb);
    hipLaunchKernelGGL(k_attn, dim3(16, B_ * H_), dim3(256), 0, stream,
                       qb, kb, vtb, yb);
    hipLaunchKernelGGL(k_gemm_proj, dim3(C_ / 128, BT / 128), dim3(256), 0, stream,
                       yb, wprojT, bproj, out);
}